// Round 8
// baseline (124.898 us; speedup 1.0000x reference)
//
#include <hip/hip_runtime.h>
#include <hip/hip_bf16.h>

#define SEQ   512
#define LPAD  64
#define RPAD  68
#define TOT   (SEQ + LPAD + RPAD)   // 644 float4 per sequence
#define C1f   14.426950408889634f    // 1/(gamma*ln2), gamma=0.1
#define K1f   0.069314718055994531f  // gamma*ln2

__device__ __forceinline__ float cost4(float4 X, float4 Y) {
  return fabsf(X.x - Y.x) + fabsf(X.y - Y.y) + fabsf(X.z - Y.z) + fabsf(X.w - Y.w);
}

// f64 lane shifts via DPP wave shifts: VALU, 0-fill at edges (0 == exp-domain BIG).
__device__ __forceinline__ double dshr1(double x) {  // lane t <- lane t+1; lane63 <- 0
  int lo = __builtin_amdgcn_update_dpp(0, __double2loint(x), 0x138, 0xF, 0xF, true);
  int hi = __builtin_amdgcn_update_dpp(0, __double2hiint(x), 0x138, 0xF, 0xF, true);
  return __hiloint2double(hi, lo);
}
__device__ __forceinline__ double dshl1(double x) {  // lane t <- lane t-1; lane0 <- 0
  int lo = __builtin_amdgcn_update_dpp(0, __double2loint(x), 0x130, 0xF, 0xF, true);
  int hi = __builtin_amdgcn_update_dpp(0, __double2hiint(x), 0x130, 0xF, 0xF, true);
  return __hiloint2double(hi, lo);
}
// lane dstlane of x receives src's lane srclane; others keep x.
// (no writelane builtin on gfx950 hipcc: readlane -> uniform, then cndmask)
__device__ __forceinline__ double inj(double x, double src, int srclane, int dstlane, int t) {
  int lo = __builtin_amdgcn_readlane(__double2loint(src), srclane);
  int hi = __builtin_amdgcn_readlane(__double2hiint(src), srclane);
  double s = __hiloint2double(hi, lo);
  return (t == dstlane) ? s : x;
}
__device__ __forceinline__ double pow2i(int k) {     // 2^k exactly, |k| <= ~500
  union { unsigned long long u; double d; } v;
  v.u = ((unsigned long long)(1023 + k)) << 52;
  return v.d;
}

// ---- slot-major band mapping: u = lane + 64*s, s in {0,1} ----
// pair n covers diags 2n+1, 2n+2. Cell u: i = n-62+u', where slot0 u'=t, slot1
// u'=t+64. Window loads (all contiguous 16B/lane, conflict-free):
//   X0 = x[n-62+t]  X1 = x[n+2+t]
//   Ya = y[n+63-t] (s0 odd)  Yb = y[n+64-t] (s0 even)
//   Yc = y[n-1-t]  (s1 odd)  Yd = y[n-t]    (s1 even)
#define DECLSET(s) \
  float4 X0##s, X1##s, Ya##s, Yb##s, Yc##s, Yd##s; \
  double Po0##s, Po1##s, Pe0##s, Pe1##s; int k1##s, k2##s;

#define LOADW(s, m) do { \
    X0##s = pXa[m]; X1##s = pXb[m]; \
    Ya##s = pYa[m]; Yb##s = pYb[m]; Yc##s = pYc[m]; Yd##s = pYd[m]; } while (0)

#define COMPP(s, bump) do { \
    k1##s = (bump) >> 1; k2##s = (bump) - k1##s; \
    float _f1 = (float)k1##s, _f2 = (float)k2##s; \
    Po0##s = (double)exp2f(fmaf(cost4(X0##s, Ya##s), -C1f, _f1)); \
    Po1##s = (double)exp2f(fmaf(cost4(X1##s, Yc##s), -C1f, _f1)); \
    Pe0##s = (double)exp2f(fmaf(cost4(X0##s, Yb##s), -C1f, _f2)); \
    Pe1##s = (double)exp2f(fmaf(cost4(X1##s, Yd##s), -C1f, _f2)); } while (0)

// odd diag: out[u] = P*(d2[u] + d1[u] + d1[u+1]); even: P*(d2[u] + d1[u-1] + d1[u])
// s0/s1 boundary: u=63's d1[u+1] = slot1 lane0; u=64's d1[u-1] = slot0 lane63.
#define CHAIN(s) do { \
    double _s2p = pow2i(k2prev), _s1c = pow2i(k1##s); \
    double _shr0 = inj(dshr1(dB0), dB1, 0, 63, t); \
    double _shr1 = dshr1(dB1); \
    double _nA0 = Po0##s * fma(dA0, _s2p, dB0 + _shr0); \
    double _nA1 = Po1##s * fma(dA1, _s2p, dB1 + _shr1); \
    double _shl0 = dshl1(_nA0); \
    double _shl1 = inj(dshl1(_nA1), _nA0, 63, 0, t); \
    double _nB0 = Pe0##s * fma(dB0, _s1c, _shl0 + _nA0); \
    double _nB1 = Pe1##s * fma(dB1, _s1c, _shl1 + _nA1); \
    dA0 = _nA0; dA1 = _nA1; dB0 = _nB0; dB1 = _nB1; } while (0)

// lag-2 reactive renorm feedback; center cell u=63 = lane63 slot0 (always valid).
#define FEEDBACK(s) do { \
    int _hib = __builtin_amdgcn_readlane(__double2hiint(dB0), 63); \
    int _def = 1023 - ((_hib >> 20) & 0x7ff); \
    Ktot += bq0; \
    int _nb = _def - bq1; _nb = _nb < -250 ? -250 : (_nb > 250 ? 250 : _nb); \
    bq0 = bq1; bq1 = _nb; k2prev = k2##s; } while (0)

// Blocks 0..95: banded soft-DTW per extended batch element -> ws[b].
// Block 96: KL + transition-count losses -> ws[96..98]. Runs concurrently.
__global__ __launch_bounds__(256, 1) void sdtw_fused_kernel(
    const float* __restrict__ at,    // [32,512,4]
    const float* __restrict__ mu,    // [32,64]
    const float* __restrict__ lv,    // [32,64]
    const float* __restrict__ ptc,   // [32,1]
    const float* __restrict__ gt,    // [32,512,4]
    float* __restrict__ ws)          // [0..95]=v, [96]=klS, [97]=auxS, [98]=trS
{
  __shared__ float4 sx[TOT];
  __shared__ float4 sy[TOT];
  __shared__ float s_g[32], s_ps[32], s_kl[32];

  const int blk = blockIdx.x;
  const int t   = threadIdx.x;

  if (blk < 96) {
    const float* xs;
    const float* ys;
    if (blk < 32)      { xs = at + (size_t)blk        * SEQ * 4; ys = gt + (size_t)blk * SEQ * 4; }
    else if (blk < 64) { xs = at + (size_t)(blk - 32) * SEQ * 4; ys = xs; }
    else               { xs = gt + (size_t)(blk - 64) * SEQ * 4; ys = xs; }

    for (int i = t; i < LPAD; i += 256) {
      sx[i] = make_float4(0.f, 0.f, 0.f, 0.f);
      sy[i] = make_float4(0.f, 0.f, 0.f, 0.f);
    }
    for (int i = LPAD + SEQ + t; i < TOT; i += 256) {
      sx[i] = make_float4(0.f, 0.f, 0.f, 0.f);
      sy[i] = make_float4(0.f, 0.f, 0.f, 0.f);
    }
    for (int i = t; i < SEQ; i += 256) {
      sx[LPAD + i] = ((const float4*)xs)[i];
      sy[LPAD + i] = ((const float4*)ys)[i];
    }
    __syncthreads();
    if (t >= 64) return;   // single wave runs the wavefront; no more barriers

    const float4* sxp = sx + LPAD;
    const float4* syp = sy + LPAD;
    // per-lane window base pointers (indexed by pair number m)
    const float4* pXa = sxp + (-62 + t);
    const float4* pXb = sxp + (  2 + t);
    const float4* pYa = syp + ( 63 - t);
    const float4* pYb = syp + ( 64 - t);
    const float4* pYc = syp + ( -1 - t);
    const float4* pYd = syp + (  0 - t);

    // state init: diag -1 (dA) = 0; diag 0 (dB): (0,0) at u=63 = lane63 slot0.
    float a0 = -C1f * cost4(sxp[0], syp[0]);
    int   n0 = (int)floorf(a0);
    double e00 = (double)exp2f(a0 - (float)n0);
    double dA0 = 0.0, dA1 = 0.0;
    double dB0 = (t == 63) ? e00 : 0.0, dB1 = 0.0;
    int Ktot = -n0;
    int bq0 = 0, bq1 = 0, k2prev = 0;

    DECLSET(0) DECLSET(1) DECLSET(2)

    // prologue: windows for pairs 0,1,2; P for pair 0 (bump 0)
    LOADW(0, 0); LOADW(1, 1); LOADW(2, 2);
    COMPP(0, 0);

    // steady: phase n = {load W(n+3), compute P(n+1), chain(n), feedback}
    #pragma unroll 1
    for (int g = 0; g < 169; ++g) {
      const int n = 3 * g;
      LOADW(0, n + 3); COMPP(1, bq1); CHAIN(0); FEEDBACK(0);
      LOADW(1, n + 4); COMPP(2, bq1); CHAIN(1); FEEDBACK(1);
      LOADW(2, n + 5); COMPP(0, bq1); CHAIN(2); FEEDBACK(2);
    }
    // epilogue: pairs 507..510
    LOADW(0, 510); COMPP(1, bq1); CHAIN(0); FEEDBACK(0);   // n=507
    COMPP(2, bq1); CHAIN(1); FEEDBACK(1);                  // n=508
    COMPP(0, bq1); CHAIN(2); FEEDBACK(2);                  // n=509
    CHAIN(0);                                              // n=510
    Ktot += bq0;

    if (t == 63) {
      // final cell (511,511) = u=63 on diag 1022 -> lane63 slot0
      unsigned long long bits = __double_as_longlong(dB0);
      int ee = (int)((bits >> 52) & 0x7ffull);
      double mant = __longlong_as_double((bits & 0xFFFFFFFFFFFFFull) | (1023ull << 52));
      double l2 = (double)(ee - 1023) + (double)__log2f((float)mant);
      ws[blk] = (float)(-(double)K1f * (l2 - (double)Ktot));
    }
    return;
  }

  // ---------- loss block (blk == 96), 256 threads: 8 per batch element ----------
  const int b = t >> 3, seg = t & 7;

  float s = 0.f;
  {
    const float* mb = mu + b * 64 + seg * 8;
    const float* lb = lv + b * 64 + seg * 8;
    #pragma unroll
    for (int z = 0; z < 8; ++z) {
      float m = mb[z], l = lb[z];
      s += 1.0f + l - m * m - __expf(l);
    }
  }
  s += __shfl_down(s, 4, 8);
  s += __shfl_down(s, 2, 8);
  s += __shfl_down(s, 1, 8);

  float g = 0.f, ps = 0.f;
  {
    const int n0 = seg * 64;
    const int nstart = (seg == 0) ? 1 : n0;
    const float* gb = gt + (size_t)b * SEQ * 4 + 2;
    const float* ab = at + (size_t)b * SEQ * 4 + 2;
    float pg = gb[(nstart - 1) * 4];
    float pp = 1.0f / (1.0f + __expf((0.5f - ab[(nstart - 1) * 4]) * 10.0f));
    for (int n = nstart; n < n0 + 64; ++n) {
      float cg = gb[n * 4]; g += fabsf(cg - pg); pg = cg;
      float cp = 1.0f / (1.0f + __expf((0.5f - ab[n * 4]) * 10.0f));
      ps += fabsf(cp - pp); pp = cp;
    }
  }
  g  += __shfl_down(g, 4, 8);  g  += __shfl_down(g, 2, 8);  g  += __shfl_down(g, 1, 8);
  ps += __shfl_down(ps, 4, 8); ps += __shfl_down(ps, 2, 8); ps += __shfl_down(ps, 1, 8);

  if (seg == 0) {
    s_g[b]  = g;
    s_ps[b] = ps;
    s_kl[b] = fmaxf(-0.5f * s - 0.5f, 0.0f);
  }
  __syncthreads();

  if (t < 32) {
    float gv  = s_g[t];
    float kl  = s_kl[t];
    float d   = ptc[t] - gv;  float aux = d * d;
    float e   = s_ps[t] - gv; float tr  = e * e;
    kl  += __shfl_down(kl, 16, 32); aux += __shfl_down(aux, 16, 32); tr += __shfl_down(tr, 16, 32);
    kl  += __shfl_down(kl,  8, 32); aux += __shfl_down(aux,  8, 32); tr += __shfl_down(tr,  8, 32);
    kl  += __shfl_down(kl,  4, 32); aux += __shfl_down(aux,  4, 32); tr += __shfl_down(tr,  4, 32);
    kl  += __shfl_down(kl,  2, 32); aux += __shfl_down(aux,  2, 32); tr += __shfl_down(tr,  2, 32);
    kl  += __shfl_down(kl,  1, 32); aux += __shfl_down(aux,  1, 32); tr += __shfl_down(tr,  1, 32);
    if (t == 0) { ws[96] = kl; ws[97] = aux; ws[98] = tr; }
  }
}

__global__ __launch_bounds__(64) void sdtw_combine_kernel(
    const float* __restrict__ ws, float* __restrict__ out)
{
  const int t = threadIdx.x;
  float vn = 0.f;
  if (t < 32) vn = ws[t] - 0.5f * (ws[32 + t] + ws[64 + t]);
  vn += __shfl_down(vn, 16, 32);
  vn += __shfl_down(vn,  8, 32);
  vn += __shfl_down(vn,  4, 32);
  vn += __shfl_down(vn,  2, 32);
  vn += __shfl_down(vn,  1, 32);
  if (t == 0) {
    float recon = vn * (1.0f / 1024.0f);   // mean(diag(v)) = sum/1024
    float kl    = ws[96] * (1.0f / 32.0f);
    float aux   = ws[97] * (1.0f / 32.0f);
    float tr    = ws[98] * (1.0f / 32.0f);
    out[0] = recon + kl + 0.1f * aux + 0.5f * tr;
    out[1] = recon;
    out[2] = kl;
    out[3] = aux;
    out[4] = tr;
  }
}

extern "C" void kernel_launch(void* const* d_in, const int* in_sizes, int n_in,
                              void* d_out, int out_size, void* d_ws, size_t ws_size,
                              hipStream_t stream) {
  const float* at  = (const float*)d_in[0];
  const float* mu  = (const float*)d_in[1];
  const float* lv  = (const float*)d_in[2];
  const float* ptc = (const float*)d_in[3];
  const float* gt  = (const float*)d_in[4];
  float* ws  = (float*)d_ws;
  float* out = (float*)d_out;

  sdtw_fused_kernel<<<97, 256, 0, stream>>>(at, mu, lv, ptc, gt, ws);
  sdtw_combine_kernel<<<1, 64, 0, stream>>>(ws, out);
}